// Round 11
// baseline (230.574 us; speedup 1.0000x reference)
//
#include <hip/hip_runtime.h>

// Problem constants (fixed by setup_inputs: bs=8, N=M=4096, C=128)
#define BS 8
#define NN 4096
#define MM 4096
#define CC 128
#define XT 128            // x rows per block
#define MT 128            // y rows per m-tile
#define MH 2048           // cols per block
#define NMT (MH / MT)     // 16 m-tiles per block
#define NXT (NN / XT)     // 32 x-tiles
#define NBLK (NXT * (MM / MH) * BS)   // 512 ch_tile blocks

#define FINF_BITS 0x7F800000u

typedef __attribute__((ext_vector_type(8))) short bf16x8;
typedef __attribute__((ext_vector_type(4))) float f32x4;

// RNE fp32 -> bf16 (inputs are finite normals)
__device__ inline ushort f2bf(float f) {
    unsigned u = __float_as_uint(f);
    unsigned r = (u + 0x7FFFu + ((u >> 16) & 1u)) >> 16;
    return (ushort)r;
}

// ---------------------------------------------------------------------------
// prep (identical to R8): fp32->bf16 copies of BOTH sets + exact fp32 row
// norms + rowmin/colmin=+inf + done=0 + out=0.
// ---------------------------------------------------------------------------
__global__ void ch_prep(const float* __restrict__ x, const float* __restrict__ y,
                        ushort* __restrict__ x16, ushort* __restrict__ y16,
                        float* __restrict__ xn, float* __restrict__ yn,
                        unsigned* __restrict__ rowmin, unsigned* __restrict__ colmin,
                        unsigned* __restrict__ done, float* __restrict__ out) {
    int gid = blockIdx.x * blockDim.x + threadIdx.x;
    size_t i = (size_t)gid * 4;

    float4 v = *(const float4*)(x + i);
    ushort4 o;
    o.x = f2bf(v.x); o.y = f2bf(v.y); o.z = f2bf(v.z); o.w = f2bf(v.w);
    *(ushort4*)(x16 + i) = o;
    float sx = v.x * v.x + v.y * v.y + v.z * v.z + v.w * v.w;

    float4 w = *(const float4*)(y + i);
    ushort4 p;
    p.x = f2bf(w.x); p.y = f2bf(w.y); p.z = f2bf(w.z); p.w = f2bf(w.w);
    *(ushort4*)(y16 + i) = p;
    float sy = w.x * w.x + w.y * w.y + w.z * w.z + w.w * w.w;

#pragma unroll
    for (int mask = 1; mask <= 16; mask <<= 1) {
        sx += __shfl_xor(sx, mask, 64);
        sy += __shfl_xor(sy, mask, 64);
    }
    if ((threadIdx.x & 31) == 0) {
        int row = gid >> 5;
        xn[row] = sx;
        yn[row] = sy;
    }
    if (gid < BS * NN) {
        rowmin[gid] = FINF_BITS;
        colmin[gid] = FINF_BITS;
    }
    if (gid == 0) { *done = 0u; out[0] = 0.0f; }
}

// ---------------------------------------------------------------------------
// main kernel: R8 core VERBATIM (512 thr, 8 waves = 2 row-halves x 4
// col-quarters of a 128x128 tile, acc 4x2 = 32 AGPR, x-tile in XOR-swizzled
// LDS staged from the bf16 global copy, y fragments direct from global,
// no barriers in the m-loop) + fused last-block finalize (done counter).
// The ONLY change vs the measured-155us R8 config is the finalize fusion —
// R10 changed staging AND finalize together and regressed; this isolates it.
// ---------------------------------------------------------------------------
__global__ __launch_bounds__(512) void ch_tile(
    const ushort* __restrict__ X, const ushort* __restrict__ Y,
    const float* __restrict__ xn, const float* __restrict__ yn,
    unsigned* __restrict__ rowmin, unsigned* __restrict__ colmin,
    const float* __restrict__ w1, const float* __restrict__ w2,
    unsigned* __restrict__ done, float* __restrict__ out) {

    __shared__ ushort xs[XT * CC];     // 32 KB, chunk-swizzled
    __shared__ unsigned coltile[MH];   // 8 KB
    __shared__ unsigned rowtile[XT];   // 0.5 KB

    const int b  = blockIdx.z;
    const int xt = blockIdx.x;         // 0..31
    const int mh = blockIdx.y;         // 0..1
    const int n0 = xt * XT;
    const int m0 = mh * MH;
    const int tid  = threadIdx.x;
    const int wave = tid >> 6;         // 0..7
    const int lane = tid & 63;
    const int lc   = lane & 15;        // A/B row, C col
    const int quad = lane >> 4;        // k-chunk, C row group
    const int wm = wave >> 2;          // row half (0/1)
    const int wn = wave & 3;           // col quarter (0..3)

    // ---- stage x tile into swizzled LDS (16B chunk c at slot c^(row&7)) ----
    const ushort* Xb = X + ((size_t)b * NN + n0) * CC;
#pragma unroll
    for (int s = 0; s < 4; ++s) {
        int flat = s * 512 + tid;      // 2048 chunks = 128 rows x 16
        int r = flat >> 4, c = flat & 15;
        int cs = c ^ (r & 7);
        *(bf16x8*)(xs + r * CC + cs * 8) = *(const bf16x8*)(Xb + (size_t)r * CC + c * 8);
    }
    for (int c2 = tid; c2 < MH; c2 += 512) coltile[c2] = FINF_BITS;
    if (tid < XT) rowtile[tid] = FINF_BITS;
    __syncthreads();

    float rm[4][4];
#pragma unroll
    for (int i = 0; i < 4; ++i)
#pragma unroll
        for (int r = 0; r < 4; ++r) rm[i][r] = __builtin_inff();

    const ushort* Yb  = Y + ((size_t)b * MM + m0) * CC;
    const float*  ynb = yn + (size_t)b * MM + m0;
    const float*  xnb = xn + (size_t)b * NN + n0;
    const int xrow = (wm * 64 + lc) * CC;
    const int xsw  = lc & 7;

#pragma unroll 1
    for (int mt = 0; mt < NMT; ++mt) {
        const ushort* Ymt = Yb + (size_t)(mt * MT + wn * 32 + lc) * CC + quad * 8;

        float ynr[2];
#pragma unroll
        for (int j = 0; j < 2; ++j)
            ynr[j] = ynb[mt * MT + wn * 32 + j * 16 + lc];

        f32x4 acc[4][2];
        const f32x4 z = {0.f, 0.f, 0.f, 0.f};
#pragma unroll
        for (int kt = 0; kt < 4; ++kt) {
            bf16x8 af[4], yf[2];
            const int cs = ((kt * 4 + quad) ^ xsw) * 8;
#pragma unroll
            for (int j = 0; j < 2; ++j)
                yf[j] = *(const bf16x8*)(Ymt + (size_t)j * 16 * CC + kt * 32);
#pragma unroll
            for (int i = 0; i < 4; ++i)
                af[i] = *(const bf16x8*)(xs + xrow + i * 16 * CC + cs);
#pragma unroll
            for (int j = 0; j < 2; ++j)
#pragma unroll
                for (int i = 0; i < 4; ++i)
                    acc[i][j] = __builtin_amdgcn_mfma_f32_16x16x32_bf16(
                        af[i], yf[j], (kt == 0) ? z : acc[i][j], 0, 0, 0);
        }

        // ---- epilogue: d^2 mins (sqrt/clamp deferred) ----
        float cmv[2];
#pragma unroll
        for (int j = 0; j < 2; ++j) cmv[j] = __builtin_inff();

#pragma unroll
        for (int i = 0; i < 4; ++i) {
            float4 t = *(const float4*)(xnb + wm * 64 + i * 16 + quad * 4);
            float xnr[4] = {t.x, t.y, t.z, t.w};
#pragma unroll
            for (int j = 0; j < 2; ++j) {
                f32x4 a = acc[i][j];
#pragma unroll
                for (int r = 0; r < 4; ++r) {
                    float d2 = xnr[r] + fmaf(-2.0f, a[r], ynr[j]);
                    rm[i][r] = fminf(rm[i][r], d2);
                    cmv[j]   = fminf(cmv[j], d2);
                }
            }
        }

        // col reduce across quads, then LDS atomic
#pragma unroll
        for (int mask = 16; mask <= 32; mask <<= 1)
#pragma unroll
            for (int j = 0; j < 2; ++j)
                cmv[j] = fminf(cmv[j], __shfl_xor(cmv[j], mask, 64));
        if (quad == 0) {
#pragma unroll
            for (int j = 0; j < 2; ++j)
                atomicMin(&coltile[mt * MT + wn * 32 + j * 16 + lc],
                          __float_as_uint(fmaxf(cmv[j], 0.0f)));
        }
    }

    // ---- row mins: reduce across the 16 lc lanes, LDS atomic once ----
#pragma unroll
    for (int mask = 1; mask <= 8; mask <<= 1)
#pragma unroll
        for (int i = 0; i < 4; ++i)
#pragma unroll
            for (int r = 0; r < 4; ++r)
                rm[i][r] = fminf(rm[i][r], __shfl_xor(rm[i][r], mask, 64));
    if (lc == 0) {
#pragma unroll
        for (int i = 0; i < 4; ++i)
#pragma unroll
            for (int r = 0; r < 4; ++r)
                atomicMin(&rowtile[wm * 64 + i * 16 + quad * 4 + r],
                          __float_as_uint(fmaxf(rm[i][r], 0.0f)));
    }

    // ---- flush tile minima with global atomics ----
    __syncthreads();
    if (tid < XT)
        atomicMin(&rowmin[(size_t)b * NN + n0 + tid], rowtile[tid]);
    for (int c2 = tid; c2 < MH; c2 += 512)
        atomicMin(&colmin[(size_t)b * MM + m0 + c2], coltile[c2]);

    // ---- fused finalize: last block does the weighted sqrt-sum ----
    __threadfence();                       // publish our atomics
    __shared__ unsigned isLast;
    if (tid == 0) isLast = (atomicAdd(done, 1u) == NBLK - 1) ? 1u : 0u;
    __syncthreads();
    if (isLast) {
        __threadfence();                   // acquire: see all blocks' mins
        float s = 0.f;
        for (int idx = tid; idx < BS * NN; idx += 512)
            s += w1[idx] * sqrtf(__uint_as_float(rowmin[idx])) +
                 w2[idx] * sqrtf(__uint_as_float(colmin[idx]));
#pragma unroll
        for (int off = 32; off > 0; off >>= 1) s += __shfl_down(s, off, 64);
        __shared__ float ls[8];
        if (lane == 0) ls[wave] = s;
        __syncthreads();
        if (tid == 0) {
            float t = 0.f;
#pragma unroll
            for (int k = 0; k < 8; ++k) t += ls[k];
            out[0] = 0.5f * t;
        }
    }
}

extern "C" void kernel_launch(void* const* d_in, const int* in_sizes, int n_in,
                              void* d_out, int out_size, void* d_ws, size_t ws_size,
                              hipStream_t stream) {
    const float* set1 = (const float*)d_in[0];
    const float* set2 = (const float*)d_in[1];
    const float* w1   = (const float*)d_in[2];
    const float* w2   = (const float*)d_in[3];
    float* out = (float*)d_out;

    // workspace layout (~16.5 MiB)
    ushort*   x16    = (ushort*)d_ws;                        // 8 MB
    ushort*   y16    = x16 + (size_t)BS * NN * CC;           // 8 MB
    float*    xn     = (float*)(y16 + (size_t)BS * MM * CC); // 128 KB
    float*    yn     = xn + BS * NN;                         // 128 KB
    unsigned* rowmin = (unsigned*)(yn + BS * MM);            // 128 KB (d^2 bits)
    unsigned* colmin = rowmin + BS * NN;                     // 128 KB (d^2 bits)
    unsigned* done   = colmin + BS * MM;                     // 1

    ch_prep<<<BS * NN * CC / 4 / 256, 256, 0, stream>>>(
        set1, set2, x16, y16, xn, yn, rowmin, colmin, done, out);

    dim3 grid(NXT, MM / MH, BS);
    ch_tile<<<grid, 512, 0, stream>>>(x16, y16, xn, yn, rowmin, colmin,
                                      w1, w2, done, out);
}

// Round 12
// 152.997 us; speedup vs baseline: 1.5071x; 1.5071x over previous
//
#include <hip/hip_runtime.h>

// Problem constants (fixed by setup_inputs: bs=8, N=M=4096, C=128)
#define BS 8
#define NN 4096
#define MM 4096
#define CC 128
#define XT 128            // x rows per block
#define MT 128            // y rows per m-tile
#define MH 2048           // cols per block
#define NMT (MH / MT)     // 16 m-tiles per block
#define NXT (NN / XT)     // 32 x-tiles

#define FINF_BITS 0x7F800000u

typedef __attribute__((ext_vector_type(8))) short bf16x8;
typedef __attribute__((ext_vector_type(4))) float f32x4;

// RNE fp32 -> bf16 (inputs are finite normals)
__device__ inline ushort f2bf(float f) {
    unsigned u = __float_as_uint(f);
    unsigned r = (u + 0x7FFFu + ((u >> 16) & 1u)) >> 16;
    return (ushort)r;
}

// ---------------------------------------------------------------------------
// prep (y only now): fp32->bf16 copy of set2 + exact fp32 y norms +
// rowmin/colmin=+inf + out=0. x is converted inside ch_tile (measured
// ~neutral there, saves 48 MB of prep traffic).
// ---------------------------------------------------------------------------
__global__ void ch_prep(const float* __restrict__ y,
                        ushort* __restrict__ y16, float* __restrict__ yn,
                        unsigned* __restrict__ rowmin, unsigned* __restrict__ colmin,
                        float* __restrict__ out) {
    int gid = blockIdx.x * blockDim.x + threadIdx.x;
    size_t i = (size_t)gid * 4;

    float4 w = *(const float4*)(y + i);
    ushort4 p;
    p.x = f2bf(w.x); p.y = f2bf(w.y); p.z = f2bf(w.z); p.w = f2bf(w.w);
    *(ushort4*)(y16 + i) = p;
    float sy = w.x * w.x + w.y * w.y + w.z * w.z + w.w * w.w;

    // 32 consecutive lanes cover one row (128 floats / 4)
#pragma unroll
    for (int mask = 1; mask <= 16; mask <<= 1)
        sy += __shfl_xor(sy, mask, 64);
    if ((threadIdx.x & 31) == 0)
        yn[gid >> 5] = sy;

    if (gid < BS * NN) rowmin[gid] = FINF_BITS;
    if (gid < BS * MM) colmin[gid] = FINF_BITS;
    if (gid == 0) out[0] = 0.0f;
}

// ---------------------------------------------------------------------------
// main kernel: R8 core (512 thr, 8 waves = 2 row-halves x 4 col-quarters of a
// 128x128 tile, acc 4x2 = 32 AGPR, y fragments direct from global/L2, no
// barriers in the m-loop) with IN-KERNEL x staging: fp32 x loaded, converted
// to bf16 into XOR-swizzled LDS, x-norms reduced into LDS at the same time.
// NO device-scope fence / fused finalize: R10/R11 proved __threadfence() at
// block end doubles the kernel (per-block L2 invalidate starves the y-stream).
// ---------------------------------------------------------------------------
__global__ __launch_bounds__(512) void ch_tile(
    const float* __restrict__ Xf, const ushort* __restrict__ Y,
    const float* __restrict__ yn,
    unsigned* __restrict__ rowmin, unsigned* __restrict__ colmin) {

    __shared__ ushort xs[XT * CC];     // 32 KB, chunk-swizzled
    __shared__ unsigned coltile[MH];   // 8 KB
    __shared__ unsigned rowtile[XT];   // 0.5 KB
    __shared__ float xnorm[XT];        // 0.5 KB

    const int b  = blockIdx.z;
    const int xt = blockIdx.x;         // 0..31
    const int mh = blockIdx.y;         // 0..1
    const int n0 = xt * XT;
    const int m0 = mh * MH;
    const int tid  = threadIdx.x;
    const int wave = tid >> 6;         // 0..7
    const int lane = tid & 63;
    const int lc   = lane & 15;        // A/B row, C col
    const int quad = lane >> 4;        // k-chunk, C row group
    const int wm = wave >> 2;          // row half (0/1)
    const int wn = wave & 3;           // col quarter (0..3)

    // ---- stage x tile: fp32 load -> bf16 -> swizzled LDS; norms too ----
    const float* Xb = Xf + ((size_t)b * NN + n0) * CC;
    {
        float psum[4];
#pragma unroll
        for (int s = 0; s < 4; ++s) {
            int flat = s * 512 + tid;  // 2048 chunks = 128 rows x 16
            int r = flat >> 4, c = flat & 15;
            float4 v0 = *(const float4*)(Xb + (size_t)r * CC + c * 8);
            float4 v1 = *(const float4*)(Xb + (size_t)r * CC + c * 8 + 4);
            ushort h[8] = {f2bf(v0.x), f2bf(v0.y), f2bf(v0.z), f2bf(v0.w),
                           f2bf(v1.x), f2bf(v1.y), f2bf(v1.z), f2bf(v1.w)};
            *(bf16x8*)(xs + r * CC + (c ^ (r & 7)) * 8) = *(bf16x8*)h;
            psum[s] = v0.x * v0.x + v0.y * v0.y + v0.z * v0.z + v0.w * v0.w +
                      v1.x * v1.x + v1.y * v1.y + v1.z * v1.z + v1.w * v1.w;
        }
        // 16 lanes (same tid>>4) share each row: reduce partials
#pragma unroll
        for (int mask = 1; mask <= 8; mask <<= 1)
#pragma unroll
            for (int s = 0; s < 4; ++s)
                psum[s] += __shfl_xor(psum[s], mask, 64);
        if ((tid & 15) == 0) {
#pragma unroll
            for (int s = 0; s < 4; ++s)
                xnorm[s * 32 + (tid >> 4)] = psum[s];
        }
    }
    for (int c2 = tid; c2 < MH; c2 += 512) coltile[c2] = FINF_BITS;
    if (tid < XT) rowtile[tid] = FINF_BITS;
    __syncthreads();

    // persistent x norms for this wave's rows
    float xnp[4][4];
#pragma unroll
    for (int i = 0; i < 4; ++i) {
        float4 t = *(const float4*)(&xnorm[wm * 64 + i * 16 + quad * 4]);
        xnp[i][0] = t.x; xnp[i][1] = t.y; xnp[i][2] = t.z; xnp[i][3] = t.w;
    }
    float rm[4][4];
#pragma unroll
    for (int i = 0; i < 4; ++i)
#pragma unroll
        for (int r = 0; r < 4; ++r) rm[i][r] = __builtin_inff();

    const ushort* Yb  = Y + ((size_t)b * MM + m0) * CC;
    const float*  ynb = yn + (size_t)b * MM + m0;
    const int xrow = (wm * 64 + lc) * CC;
    const int xsw  = lc & 7;

#pragma unroll 1
    for (int mt = 0; mt < NMT; ++mt) {
        const ushort* Ymt = Yb + (size_t)(mt * MT + wn * 32 + lc) * CC + quad * 8;

        float ynr[2];
#pragma unroll
        for (int j = 0; j < 2; ++j)
            ynr[j] = ynb[mt * MT + wn * 32 + j * 16 + lc];

        f32x4 acc[4][2];
        const f32x4 z = {0.f, 0.f, 0.f, 0.f};
#pragma unroll
        for (int kt = 0; kt < 4; ++kt) {
            bf16x8 af[4], yf[2];
            const int cs = ((kt * 4 + quad) ^ xsw) * 8;
#pragma unroll
            for (int j = 0; j < 2; ++j)
                yf[j] = *(const bf16x8*)(Ymt + (size_t)j * 16 * CC + kt * 32);
#pragma unroll
            for (int i = 0; i < 4; ++i)
                af[i] = *(const bf16x8*)(xs + xrow + i * 16 * CC + cs);
#pragma unroll
            for (int j = 0; j < 2; ++j)
#pragma unroll
                for (int i = 0; i < 4; ++i)
                    acc[i][j] = __builtin_amdgcn_mfma_f32_16x16x32_bf16(
                        af[i], yf[j], (kt == 0) ? z : acc[i][j], 0, 0, 0);
        }

        // ---- epilogue: d^2 mins (sqrt/clamp deferred) ----
        float cmv[2];
#pragma unroll
        for (int j = 0; j < 2; ++j) cmv[j] = __builtin_inff();

#pragma unroll
        for (int i = 0; i < 4; ++i) {
#pragma unroll
            for (int j = 0; j < 2; ++j) {
                f32x4 a = acc[i][j];
#pragma unroll
                for (int r = 0; r < 4; ++r) {
                    float d2 = xnp[i][r] + fmaf(-2.0f, a[r], ynr[j]);
                    rm[i][r] = fminf(rm[i][r], d2);
                    cmv[j]   = fminf(cmv[j], d2);
                }
            }
        }

        // col reduce across quads, then LDS atomic
#pragma unroll
        for (int mask = 16; mask <= 32; mask <<= 1)
#pragma unroll
            for (int j = 0; j < 2; ++j)
                cmv[j] = fminf(cmv[j], __shfl_xor(cmv[j], mask, 64));
        if (quad == 0) {
#pragma unroll
            for (int j = 0; j < 2; ++j)
                atomicMin(&coltile[mt * MT + wn * 32 + j * 16 + lc],
                          __float_as_uint(fmaxf(cmv[j], 0.0f)));
        }
    }

    // ---- row mins: reduce across the 16 lc lanes, LDS atomic once ----
#pragma unroll
    for (int mask = 1; mask <= 8; mask <<= 1)
#pragma unroll
        for (int i = 0; i < 4; ++i)
#pragma unroll
            for (int r = 0; r < 4; ++r)
                rm[i][r] = fminf(rm[i][r], __shfl_xor(rm[i][r], mask, 64));
    if (lc == 0) {
#pragma unroll
        for (int i = 0; i < 4; ++i)
#pragma unroll
            for (int r = 0; r < 4; ++r)
                atomicMin(&rowtile[wm * 64 + i * 16 + quad * 4 + r],
                          __float_as_uint(fmaxf(rm[i][r], 0.0f)));
    }

    // ---- flush tile minima with global atomics ----
    __syncthreads();
    if (tid < XT)
        atomicMin(&rowmin[(size_t)b * NN + n0 + tid], rowtile[tid]);
    for (int c2 = tid; c2 < MH; c2 += 512)
        atomicMin(&colmin[(size_t)b * MM + m0 + c2], coltile[c2]);
}

// ---------------------------------------------------------------------------
// finalize: total = (sum w1*sqrt(rowmin) + sum w2*sqrt(colmin)) / 2
// ---------------------------------------------------------------------------
__global__ void ch_finalize(const unsigned* __restrict__ rowmin,
                            const unsigned* __restrict__ colmin,
                            const float* __restrict__ w1,
                            const float* __restrict__ w2,
                            float* __restrict__ out) {
    int i = blockIdx.x * blockDim.x + threadIdx.x;
    int stride = gridDim.x * blockDim.x;
    float s = 0.f;
    for (int idx = i; idx < BS * NN; idx += stride)
        s += w1[idx] * sqrtf(__uint_as_float(rowmin[idx])) +
             w2[idx] * sqrtf(__uint_as_float(colmin[idx]));
#pragma unroll
    for (int off = 32; off > 0; off >>= 1) s += __shfl_down(s, off, 64);
    __shared__ float ls[4];
    int lane = threadIdx.x & 63, wv = threadIdx.x >> 6;
    if (lane == 0) ls[wv] = s;
    __syncthreads();
    if (threadIdx.x == 0) {
        float t = ls[0] + ls[1] + ls[2] + ls[3];
        atomicAdd(out, 0.5f * t);
    }
}

extern "C" void kernel_launch(void* const* d_in, const int* in_sizes, int n_in,
                              void* d_out, int out_size, void* d_ws, size_t ws_size,
                              hipStream_t stream) {
    const float* set1 = (const float*)d_in[0];
    const float* set2 = (const float*)d_in[1];
    const float* w1   = (const float*)d_in[2];
    const float* w2   = (const float*)d_in[3];
    float* out = (float*)d_out;

    // workspace layout (~8.5 MiB)
    ushort*   y16    = (ushort*)d_ws;                        // BS*MM*CC bf16 (8 MB)
    float*    yn     = (float*)(y16 + (size_t)BS * MM * CC); // 128 KB
    unsigned* rowmin = (unsigned*)(yn + BS * MM);            // 128 KB (d^2 bits)
    unsigned* colmin = rowmin + BS * NN;                     // 128 KB (d^2 bits)

    ch_prep<<<BS * MM * CC / 4 / 256, 256, 0, stream>>>(
        set2, y16, yn, rowmin, colmin, out);

    dim3 grid(NXT, MM / MH, BS);
    ch_tile<<<grid, 512, 0, stream>>>(set1, y16, yn, rowmin, colmin);

    ch_finalize<<<64, 256, 0, stream>>>(rowmin, colmin, w1, w2, out);
}

// Round 13
// 150.472 us; speedup vs baseline: 1.5323x; 1.0168x over previous
//
#include <hip/hip_runtime.h>

// Problem constants (fixed by setup_inputs: bs=8, N=M=4096, C=128)
#define BS 8
#define NN 4096
#define MM 4096
#define CC 128
#define XT 128            // x rows per block
#define MT 128            // y rows per m-tile
#define MH 2048           // cols per block
#define NMT (MH / MT)     // 16 m-tiles per block
#define NXT (NN / XT)     // 32 x-tiles

#define FINF_BITS 0x7F800000u

typedef __attribute__((ext_vector_type(8))) short bf16x8;
typedef __attribute__((ext_vector_type(4))) float f32x4;

// RNE fp32 -> bf16 (inputs are finite normals)
__device__ inline ushort f2bf(float f) {
    unsigned u = __float_as_uint(f);
    unsigned r = (u + 0x7FFFu + ((u >> 16) & 1u)) >> 16;
    return (ushort)r;
}

// ---------------------------------------------------------------------------
// prep (y only): fp32->bf16 copy of set2 + exact fp32 y norms +
// rowmin/colmin=+inf + out=0. x is converted inside ch_tile.
// ---------------------------------------------------------------------------
__global__ void ch_prep(const float* __restrict__ y,
                        ushort* __restrict__ y16, float* __restrict__ yn,
                        unsigned* __restrict__ rowmin, unsigned* __restrict__ colmin,
                        float* __restrict__ out) {
    int gid = blockIdx.x * blockDim.x + threadIdx.x;
    size_t i = (size_t)gid * 4;

    float4 w = *(const float4*)(y + i);
    ushort4 p;
    p.x = f2bf(w.x); p.y = f2bf(w.y); p.z = f2bf(w.z); p.w = f2bf(w.w);
    *(ushort4*)(y16 + i) = p;
    float sy = w.x * w.x + w.y * w.y + w.z * w.z + w.w * w.w;

#pragma unroll
    for (int mask = 1; mask <= 16; mask <<= 1)
        sy += __shfl_xor(sy, mask, 64);
    if ((threadIdx.x & 31) == 0)
        yn[gid >> 5] = sy;

    if (gid < BS * NN) rowmin[gid] = FINF_BITS;
    if (gid < BS * MM) colmin[gid] = FINF_BITS;
    if (gid == 0) out[0] = 0.0f;
}

// ---------------------------------------------------------------------------
// main kernel: R12 core, XCD-PINNED GRID. grid=(8, NXT, 2), b=blockIdx.x so
// linear_block_id % 8 == b == XCD id: all 64 blocks of batch b are dispatched
// to one XCD and share the same 1 MB y16 slice -> y-stream fully L2-resident
// (was: mixed batches per XCD, 8 MB footprint > 4 MB L2, thrash to L3).
// Core: 512 thr, 8 waves = 2 row-halves x 4 col-quarters of a 128x128 tile,
// acc 4x2 = 32 AGPR; x staged fp32->bf16 into XOR-swizzled LDS in-kernel;
// y fragments direct from global (L2); no barriers in the m-loop; no
// device-scope fences (R11: threadfence at block end doubles the kernel).
// ---------------------------------------------------------------------------
__global__ __launch_bounds__(512) void ch_tile(
    const float* __restrict__ Xf, const ushort* __restrict__ Y,
    const float* __restrict__ yn,
    unsigned* __restrict__ rowmin, unsigned* __restrict__ colmin) {

    __shared__ ushort xs[XT * CC];     // 32 KB, chunk-swizzled
    __shared__ unsigned coltile[MH];   // 8 KB
    __shared__ unsigned rowtile[XT];   // 0.5 KB
    __shared__ float xnorm[XT];        // 0.5 KB

    const int b  = blockIdx.x;         // 0..7  -> XCD pin (linear id % 8 == b)
    const int xt = blockIdx.y;         // 0..31
    const int mh = blockIdx.z;         // 0..1
    const int n0 = xt * XT;
    const int m0 = mh * MH;
    const int tid  = threadIdx.x;
    const int wave = tid >> 6;         // 0..7
    const int lane = tid & 63;
    const int lc   = lane & 15;        // A/B row, C col
    const int quad = lane >> 4;        // k-chunk, C row group
    const int wm = wave >> 2;          // row half (0/1)
    const int wn = wave & 3;           // col quarter (0..3)

    // ---- stage x tile: fp32 load -> bf16 -> swizzled LDS; norms too ----
    const float* Xb = Xf + ((size_t)b * NN + n0) * CC;
    {
        float psum[4];
#pragma unroll
        for (int s = 0; s < 4; ++s) {
            int flat = s * 512 + tid;  // 2048 chunks = 128 rows x 16
            int r = flat >> 4, c = flat & 15;
            float4 v0 = *(const float4*)(Xb + (size_t)r * CC + c * 8);
            float4 v1 = *(const float4*)(Xb + (size_t)r * CC + c * 8 + 4);
            ushort h[8] = {f2bf(v0.x), f2bf(v0.y), f2bf(v0.z), f2bf(v0.w),
                           f2bf(v1.x), f2bf(v1.y), f2bf(v1.z), f2bf(v1.w)};
            *(bf16x8*)(xs + r * CC + (c ^ (r & 7)) * 8) = *(bf16x8*)h;
            psum[s] = v0.x * v0.x + v0.y * v0.y + v0.z * v0.z + v0.w * v0.w +
                      v1.x * v1.x + v1.y * v1.y + v1.z * v1.z + v1.w * v1.w;
        }
#pragma unroll
        for (int mask = 1; mask <= 8; mask <<= 1)
#pragma unroll
            for (int s = 0; s < 4; ++s)
                psum[s] += __shfl_xor(psum[s], mask, 64);
        if ((tid & 15) == 0) {
#pragma unroll
            for (int s = 0; s < 4; ++s)
                xnorm[s * 32 + (tid >> 4)] = psum[s];
        }
    }
    for (int c2 = tid; c2 < MH; c2 += 512) coltile[c2] = FINF_BITS;
    if (tid < XT) rowtile[tid] = FINF_BITS;
    __syncthreads();

    // persistent x norms for this wave's rows
    float xnp[4][4];
#pragma unroll
    for (int i = 0; i < 4; ++i) {
        float4 t = *(const float4*)(&xnorm[wm * 64 + i * 16 + quad * 4]);
        xnp[i][0] = t.x; xnp[i][1] = t.y; xnp[i][2] = t.z; xnp[i][3] = t.w;
    }
    float rm[4][4];
#pragma unroll
    for (int i = 0; i < 4; ++i)
#pragma unroll
        for (int r = 0; r < 4; ++r) rm[i][r] = __builtin_inff();

    const ushort* Yb  = Y + ((size_t)b * MM + m0) * CC;
    const float*  ynb = yn + (size_t)b * MM + m0;
    const int xrow = (wm * 64 + lc) * CC;
    const int xsw  = lc & 7;

#pragma unroll 1
    for (int mt = 0; mt < NMT; ++mt) {
        const ushort* Ymt = Yb + (size_t)(mt * MT + wn * 32 + lc) * CC + quad * 8;

        float ynr[2];
#pragma unroll
        for (int j = 0; j < 2; ++j)
            ynr[j] = ynb[mt * MT + wn * 32 + j * 16 + lc];

        f32x4 acc[4][2];
        const f32x4 z = {0.f, 0.f, 0.f, 0.f};
#pragma unroll
        for (int kt = 0; kt < 4; ++kt) {
            bf16x8 af[4], yf[2];
            const int cs = ((kt * 4 + quad) ^ xsw) * 8;
#pragma unroll
            for (int j = 0; j < 2; ++j)
                yf[j] = *(const bf16x8*)(Ymt + (size_t)j * 16 * CC + kt * 32);
#pragma unroll
            for (int i = 0; i < 4; ++i)
                af[i] = *(const bf16x8*)(xs + xrow + i * 16 * CC + cs);
#pragma unroll
            for (int j = 0; j < 2; ++j)
#pragma unroll
                for (int i = 0; i < 4; ++i)
                    acc[i][j] = __builtin_amdgcn_mfma_f32_16x16x32_bf16(
                        af[i], yf[j], (kt == 0) ? z : acc[i][j], 0, 0, 0);
        }

        // ---- epilogue: d^2 mins (sqrt/clamp deferred) ----
        float cmv[2];
#pragma unroll
        for (int j = 0; j < 2; ++j) cmv[j] = __builtin_inff();

#pragma unroll
        for (int i = 0; i < 4; ++i) {
#pragma unroll
            for (int j = 0; j < 2; ++j) {
                f32x4 a = acc[i][j];
#pragma unroll
                for (int r = 0; r < 4; ++r) {
                    float d2 = xnp[i][r] + fmaf(-2.0f, a[r], ynr[j]);
                    rm[i][r] = fminf(rm[i][r], d2);
                    cmv[j]   = fminf(cmv[j], d2);
                }
            }
        }

        // col reduce across quads, then LDS atomic
#pragma unroll
        for (int mask = 16; mask <= 32; mask <<= 1)
#pragma unroll
            for (int j = 0; j < 2; ++j)
                cmv[j] = fminf(cmv[j], __shfl_xor(cmv[j], mask, 64));
        if (quad == 0) {
#pragma unroll
            for (int j = 0; j < 2; ++j)
                atomicMin(&coltile[mt * MT + wn * 32 + j * 16 + lc],
                          __float_as_uint(fmaxf(cmv[j], 0.0f)));
        }
    }

    // ---- row mins: reduce across the 16 lc lanes, LDS atomic once ----
#pragma unroll
    for (int mask = 1; mask <= 8; mask <<= 1)
#pragma unroll
        for (int i = 0; i < 4; ++i)
#pragma unroll
            for (int r = 0; r < 4; ++r)
                rm[i][r] = fminf(rm[i][r], __shfl_xor(rm[i][r], mask, 64));
    if (lc == 0) {
#pragma unroll
        for (int i = 0; i < 4; ++i)
#pragma unroll
            for (int r = 0; r < 4; ++r)
                atomicMin(&rowtile[wm * 64 + i * 16 + quad * 4 + r],
                          __float_as_uint(fmaxf(rm[i][r], 0.0f)));
    }

    // ---- flush tile minima with global atomics ----
    __syncthreads();
    if (tid < XT)
        atomicMin(&rowmin[(size_t)b * NN + n0 + tid], rowtile[tid]);
    for (int c2 = tid; c2 < MH; c2 += 512)
        atomicMin(&colmin[(size_t)b * MM + m0 + c2], coltile[c2]);
}

// ---------------------------------------------------------------------------
// finalize: total = (sum w1*sqrt(rowmin) + sum w2*sqrt(colmin)) / 2
// ---------------------------------------------------------------------------
__global__ void ch_finalize(const unsigned* __restrict__ rowmin,
                            const unsigned* __restrict__ colmin,
                            const float* __restrict__ w1,
                            const float* __restrict__ w2,
                            float* __restrict__ out) {
    int i = blockIdx.x * blockDim.x + threadIdx.x;
    int stride = gridDim.x * blockDim.x;
    float s = 0.f;
    for (int idx = i; idx < BS * NN; idx += stride)
        s += w1[idx] * sqrtf(__uint_as_float(rowmin[idx])) +
             w2[idx] * sqrtf(__uint_as_float(colmin[idx]));
#pragma unroll
    for (int off = 32; off > 0; off >>= 1) s += __shfl_down(s, off, 64);
    __shared__ float ls[4];
    int lane = threadIdx.x & 63, wv = threadIdx.x >> 6;
    if (lane == 0) ls[wv] = s;
    __syncthreads();
    if (threadIdx.x == 0) {
        float t = ls[0] + ls[1] + ls[2] + ls[3];
        atomicAdd(out, 0.5f * t);
    }
}

extern "C" void kernel_launch(void* const* d_in, const int* in_sizes, int n_in,
                              void* d_out, int out_size, void* d_ws, size_t ws_size,
                              hipStream_t stream) {
    const float* set1 = (const float*)d_in[0];
    const float* set2 = (const float*)d_in[1];
    const float* w1   = (const float*)d_in[2];
    const float* w2   = (const float*)d_in[3];
    float* out = (float*)d_out;

    // workspace layout (~8.5 MiB)
    ushort*   y16    = (ushort*)d_ws;                        // BS*MM*CC bf16 (8 MB)
    float*    yn     = (float*)(y16 + (size_t)BS * MM * CC); // 128 KB
    unsigned* rowmin = (unsigned*)(yn + BS * MM);            // 128 KB (d^2 bits)
    unsigned* colmin = rowmin + BS * NN;                     // 128 KB (d^2 bits)

    ch_prep<<<BS * MM * CC / 4 / 256, 256, 0, stream>>>(
        set2, y16, yn, rowmin, colmin, out);

    dim3 grid(BS, NXT, MM / MH);   // b fastest -> linear id % 8 == b == XCD
    ch_tile<<<grid, 512, 0, stream>>>(set1, y16, yn, rowmin, colmin);

    ch_finalize<<<64, 256, 0, stream>>>(rowmin, colmin, w1, w2, out);
}

// Round 14
// 130.927 us; speedup vs baseline: 1.7611x; 1.1493x over previous
//
#include <hip/hip_runtime.h>

// Problem constants (fixed by setup_inputs: bs=8, N=M=4096, C=128)
#define BS 8
#define NN 4096
#define MM 4096
#define CC 128
#define XT 128            // x rows per block
#define YT 64             // y rows per staged tile
#define MH 2048           // y rows per block
#define NYT (MH / YT)     // 32 y-tiles per block
#define NXT (NN / XT)     // 32 x-tiles

#define FINF_BITS 0x7F800000u

typedef __attribute__((ext_vector_type(8))) short bf16x8;
typedef __attribute__((ext_vector_type(4))) float f32x4;

// RNE fp32 -> bf16 (inputs are finite normals)
__device__ inline ushort f2bf(float f) {
    unsigned u = __float_as_uint(f);
    unsigned r = (u + 0x7FFFu + ((u >> 16) & 1u)) >> 16;
    return (ushort)r;
}

// ---------------------------------------------------------------------------
// prep (y only): fp32->bf16 copy of set2 + exact fp32 y norms +
// rowmin/colmin=+inf + out=0. x is converted inside ch_tile.
// ---------------------------------------------------------------------------
__global__ void ch_prep(const float* __restrict__ y,
                        ushort* __restrict__ y16, float* __restrict__ yn,
                        unsigned* __restrict__ rowmin, unsigned* __restrict__ colmin,
                        float* __restrict__ out) {
    int gid = blockIdx.x * blockDim.x + threadIdx.x;
    size_t i = (size_t)gid * 4;

    float4 w = *(const float4*)(y + i);
    ushort4 p;
    p.x = f2bf(w.x); p.y = f2bf(w.y); p.z = f2bf(w.z); p.w = f2bf(w.w);
    *(ushort4*)(y16 + i) = p;
    float sy = w.x * w.x + w.y * w.y + w.z * w.z + w.w * w.w;

#pragma unroll
    for (int mask = 1; mask <= 16; mask <<= 1)
        sy += __shfl_xor(sy, mask, 64);
    if ((threadIdx.x & 31) == 0)
        yn[gid >> 5] = sy;

    if (gid < BS * NN) rowmin[gid] = FINF_BITS;
    if (gid < BS * MM) colmin[gid] = FINF_BITS;
    if (gid == 0) out[0] = 0.0f;
}

// ---------------------------------------------------------------------------
// main kernel (R14): async-staged y through a double-buffered LDS tile.
//  - 256 thr, 4 waves = 2x2 quadrants; per y-tile (128x64) each wave does
//    4i x 2j x 4kt = 32 MFMAs, acc 4x2 = 32 AGPR.
//  - y-tile (64x128 bf16 = 16 KB) staged via global_load_lds width-16 into
//    ys[2]; tile mt+1 issued BEFORE computing tile mt, drained by the single
//    barrier one full compute later -> staging latency fully hidden; the
//    MFMA chain consumes only ds_read_b128 (no vmcnt waits in the K-loop).
//  - global_load_lds forces flat lane-order LDS writes, so the GLOBAL source
//    chunk is swizzled (c ^ (row&15)); reads use slot (kt*4+quad)^lc ->
//    bank-minimum access (no excess conflicts).
//  - x staged fp32->bf16 swizzled + in-LDS norms (proven R12); XCD-pinned
//    grid (proven R13: FETCH 41->12 MB); no device-scope fences (R11).
// ---------------------------------------------------------------------------
__global__ __launch_bounds__(256) void ch_tile(
    const float* __restrict__ Xf, const ushort* __restrict__ Y,
    const float* __restrict__ yn,
    unsigned* __restrict__ rowmin, unsigned* __restrict__ colmin) {

    __shared__ ushort xs[XT * CC];       // 32 KB, chunk-swizzled (r&7)
    __shared__ ushort ys[2][YT * CC];    // 2 x 16 KB, chunk-swizzled (r&15)
    __shared__ unsigned coltile[MH];     // 8 KB
    __shared__ unsigned rowtile[XT];     // 0.5 KB
    __shared__ float xnorm[XT];          // 0.5 KB

    const int b  = blockIdx.x;           // 0..7 -> XCD pin (linear id % 8 == b)
    const int xt = blockIdx.y;           // 0..31
    const int mh = blockIdx.z;           // 0..1
    const int n0 = xt * XT;
    const int m0 = mh * MH;
    const int tid  = threadIdx.x;
    const int wave = tid >> 6;           // 0..3
    const int lane = tid & 63;
    const int lc   = lane & 15;          // A/B row, C col
    const int quad = lane >> 4;          // k-chunk, C row group
    const int wm = wave >> 1;            // row half (0/1)
    const int wn = wave & 1;             // col half (0/1)

    const ushort* Yb = Y + ((size_t)b * MM + m0) * CC;

    // ---- stage x tile: fp32 -> bf16 -> swizzled LDS; norms too ----
    const float* Xb = Xf + ((size_t)b * NN + n0) * CC;
    {
        float psum[8];
#pragma unroll
        for (int s = 0; s < 8; ++s) {
            int flat = s * 256 + tid;    // 2048 chunks = 128 rows x 16
            int r = flat >> 4, c = flat & 15;
            float4 v0 = *(const float4*)(Xb + (size_t)r * CC + c * 8);
            float4 v1 = *(const float4*)(Xb + (size_t)r * CC + c * 8 + 4);
            ushort h[8] = {f2bf(v0.x), f2bf(v0.y), f2bf(v0.z), f2bf(v0.w),
                           f2bf(v1.x), f2bf(v1.y), f2bf(v1.z), f2bf(v1.w)};
            *(bf16x8*)(xs + r * CC + (c ^ (r & 7)) * 8) = *(bf16x8*)h;
            psum[s] = v0.x * v0.x + v0.y * v0.y + v0.z * v0.z + v0.w * v0.w +
                      v1.x * v1.x + v1.y * v1.y + v1.z * v1.z + v1.w * v1.w;
        }
#pragma unroll
        for (int mask = 1; mask <= 8; mask <<= 1)
#pragma unroll
            for (int s = 0; s < 8; ++s)
                psum[s] += __shfl_xor(psum[s], mask, 64);
        if ((tid & 15) == 0) {
#pragma unroll
            for (int s = 0; s < 8; ++s)
                xnorm[s * 16 + (tid >> 4)] = psum[s];
        }
    }
    for (int c2 = tid; c2 < MH; c2 += 256) coltile[c2] = FINF_BITS;
    if (tid < XT) rowtile[tid] = FINF_BITS;

    // ---- async-stage y tile 0 into ys[0] (global chunk swizzled) ----
#pragma unroll
    for (int s = 0; s < 4; ++s) {
        int f = s * 256 + tid;           // 1024 chunks = 64 rows x 16
        int r = f >> 4, c = f & 15;
        const ushort* g = Yb + (size_t)r * CC + (c ^ (r & 15)) * 8;
        ushort* l = ys[0] + (s * 256 + wave * 64) * 8;   // uniform; HW adds lane*16
        __builtin_amdgcn_global_load_lds(
            (const __attribute__((address_space(1))) void*)g,
            (__attribute__((address_space(3))) void*)l, 16, 0, 0);
    }

    __syncthreads();   // drains x LDS writes + y0 staging (vmcnt(0) + barrier)

    // persistent x norms for this wave's rows
    float xnp[4][4];
#pragma unroll
    for (int i = 0; i < 4; ++i) {
        float4 t = *(const float4*)(&xnorm[wm * 64 + i * 16 + quad * 4]);
        xnp[i][0] = t.x; xnp[i][1] = t.y; xnp[i][2] = t.z; xnp[i][3] = t.w;
    }
    float rm[4][4];
#pragma unroll
    for (int i = 0; i < 4; ++i)
#pragma unroll
        for (int r = 0; r < 4; ++r) rm[i][r] = __builtin_inff();

    const float* ynb = yn + (size_t)b * MM + m0;
    const int xrow = (wm * 64 + lc) * CC;
    const int yrow = (wn * 32 + lc) * CC;
    const int xsw  = lc & 7;

#pragma unroll 1
    for (int mt = 0; mt < NYT; ++mt) {
        if (mt) __syncthreads();         // stage(mt) drained; prev reads done

        // ---- async-stage tile mt+1 into the other buffer ----
        if (mt + 1 < NYT) {
            const ushort* Ysrc = Yb + (size_t)(mt + 1) * YT * CC;
            ushort* dstb = ys[(mt + 1) & 1];
#pragma unroll
            for (int s = 0; s < 4; ++s) {
                int f = s * 256 + tid;
                int r = f >> 4, c = f & 15;
                const ushort* g = Ysrc + (size_t)r * CC + (c ^ (r & 15)) * 8;
                ushort* l = dstb + (s * 256 + wave * 64) * 8;
                __builtin_amdgcn_global_load_lds(
                    (const __attribute__((address_space(1))) void*)g,
                    (__attribute__((address_space(3))) void*)l, 16, 0, 0);
            }
        }

        const ushort* yl = ys[mt & 1];

        float ynr[2];
#pragma unroll
        for (int j = 0; j < 2; ++j)
            ynr[j] = ynb[mt * YT + wn * 32 + j * 16 + lc];

        f32x4 acc[4][2];
        const f32x4 z = {0.f, 0.f, 0.f, 0.f};
#pragma unroll
        for (int kt = 0; kt < 4; ++kt) {
            bf16x8 af[4], yf[2];
            const int cx = ((kt * 4 + quad) ^ xsw) * 8;
            const int cy = ((kt * 4 + quad) ^ lc) * 8;   // row&15 == lc for y rows
#pragma unroll
            for (int j = 0; j < 2; ++j)
                yf[j] = *(const bf16x8*)(yl + yrow + j * 16 * CC + cy);
#pragma unroll
            for (int i = 0; i < 4; ++i)
                af[i] = *(const bf16x8*)(xs + xrow + i * 16 * CC + cx);
#pragma unroll
            for (int j = 0; j < 2; ++j)
#pragma unroll
                for (int i = 0; i < 4; ++i)
                    acc[i][j] = __builtin_amdgcn_mfma_f32_16x16x32_bf16(
                        af[i], yf[j], (kt == 0) ? z : acc[i][j], 0, 0, 0);
        }

        // ---- epilogue: d^2 mins (sqrt/clamp deferred) ----
        float cmv[2];
#pragma unroll
        for (int j = 0; j < 2; ++j) cmv[j] = __builtin_inff();

#pragma unroll
        for (int i = 0; i < 4; ++i) {
#pragma unroll
            for (int j = 0; j < 2; ++j) {
                f32x4 a = acc[i][j];
#pragma unroll
                for (int r = 0; r < 4; ++r) {
                    float d2 = xnp[i][r] + fmaf(-2.0f, a[r], ynr[j]);
                    rm[i][r] = fminf(rm[i][r], d2);
                    cmv[j]   = fminf(cmv[j], d2);
                }
            }
        }

        // col reduce across quads, then LDS atomic
#pragma unroll
        for (int mask = 16; mask <= 32; mask <<= 1)
#pragma unroll
            for (int j = 0; j < 2; ++j)
                cmv[j] = fminf(cmv[j], __shfl_xor(cmv[j], mask, 64));
        if (quad == 0) {
#pragma unroll
            for (int j = 0; j < 2; ++j)
                atomicMin(&coltile[mt * YT + wn * 32 + j * 16 + lc],
                          __float_as_uint(fmaxf(cmv[j], 0.0f)));
        }
    }

    // ---- row mins: reduce across the 16 lc lanes, LDS atomic once ----
#pragma unroll
    for (int mask = 1; mask <= 8; mask <<= 1)
#pragma unroll
        for (int i = 0; i < 4; ++i)
#pragma unroll
            for (int r = 0; r < 4; ++r)
                rm[i][r] = fminf(rm[i][r], __shfl_xor(rm[i][r], mask, 64));
    if (lc == 0) {
#pragma unroll
        for (int i = 0; i < 4; ++i)
#pragma unroll
            for (int r = 0; r < 4; ++r)
                atomicMin(&rowtile[wm * 64 + i * 16 + quad * 4 + r],
                          __float_as_uint(fmaxf(rm[i][r], 0.0f)));
    }

    // ---- flush tile minima with global atomics ----
    __syncthreads();
    if (tid < XT)
        atomicMin(&rowmin[(size_t)b * NN + n0 + tid], rowtile[tid]);
    for (int c2 = tid; c2 < MH; c2 += 256)
        atomicMin(&colmin[(size_t)b * MM + m0 + c2], coltile[c2]);
}

// ---------------------------------------------------------------------------
// finalize: total = (sum w1*sqrt(rowmin) + sum w2*sqrt(colmin)) / 2
// ---------------------------------------------------------------------------
__global__ void ch_finalize(const unsigned* __restrict__ rowmin,
                            const unsigned* __restrict__ colmin,
                            const float* __restrict__ w1,
                            const float* __restrict__ w2,
                            float* __restrict__ out) {
    int i = blockIdx.x * blockDim.x + threadIdx.x;
    int stride = gridDim.x * blockDim.x;
    float s = 0.f;
    for (int idx = i; idx < BS * NN; idx += stride)
        s += w1[idx] * sqrtf(__uint_as_float(rowmin[idx])) +
             w2[idx] * sqrtf(__uint_as_float(colmin[idx]));
#pragma unroll
    for (int off = 32; off > 0; off >>= 1) s += __shfl_down(s, off, 64);
    __shared__ float ls[4];
    int lane = threadIdx.x & 63, wv = threadIdx.x >> 6;
    if (lane == 0) ls[wv] = s;
    __syncthreads();
    if (threadIdx.x == 0) {
        float t = ls[0] + ls[1] + ls[2] + ls[3];
        atomicAdd(out, 0.5f * t);
    }
}

extern "C" void kernel_launch(void* const* d_in, const int* in_sizes, int n_in,
                              void* d_out, int out_size, void* d_ws, size_t ws_size,
                              hipStream_t stream) {
    const float* set1 = (const float*)d_in[0];
    const float* set2 = (const float*)d_in[1];
    const float* w1   = (const float*)d_in[2];
    const float* w2   = (const float*)d_in[3];
    float* out = (float*)d_out;

    // workspace layout (~8.5 MiB)
    ushort*   y16    = (ushort*)d_ws;                        // BS*MM*CC bf16 (8 MB)
    float*    yn     = (float*)(y16 + (size_t)BS * MM * CC); // 128 KB
    unsigned* rowmin = (unsigned*)(yn + BS * MM);            // 128 KB (d^2 bits)
    unsigned* colmin = rowmin + BS * NN;                     // 128 KB (d^2 bits)

    ch_prep<<<BS * MM * CC / 4 / 256, 256, 0, stream>>>(
        set2, y16, yn, rowmin, colmin, out);

    dim3 grid(BS, NXT, MM / MH);   // b fastest -> linear id % 8 == b == XCD
    ch_tile<<<grid, 256, 0, stream>>>(set1, y16, yn, rowmin, colmin);

    ch_finalize<<<64, 256, 0, stream>>>(rowmin, colmin, w1, w2, out);
}

// Round 15
// 128.036 us; speedup vs baseline: 1.8009x; 1.0226x over previous
//
#include <hip/hip_runtime.h>

// Problem constants (fixed by setup_inputs: bs=8, N=M=4096, C=128)
#define BS 8
#define NN 4096
#define MM 4096
#define CC 128
#define XT 128            // x rows per block
#define YT 128            // y rows per tile
#define MH 2048           // y rows per block
#define NMT (MH / YT)     // 16 y-tiles per block
#define NXT (NN / XT)     // 32 x-tiles

#define FINF_BITS 0x7F800000u

typedef __attribute__((ext_vector_type(8))) short bf16x8;
typedef __attribute__((ext_vector_type(4))) float f32x4;

// RNE fp32 -> bf16 (inputs are finite normals)
__device__ inline ushort f2bf(float f) {
    unsigned u = __float_as_uint(f);
    unsigned r = (u + 0x7FFFu + ((u >> 16) & 1u)) >> 16;
    return (ushort)r;
}

// ---------------------------------------------------------------------------
// prep (y only): fp32->bf16 copy of set2 + exact fp32 y norms +
// rowmin/colmin=+inf + out=0. x is converted inside ch_tile.
// ---------------------------------------------------------------------------
__global__ void ch_prep(const float* __restrict__ y,
                        ushort* __restrict__ y16, float* __restrict__ yn,
                        unsigned* __restrict__ rowmin, unsigned* __restrict__ colmin,
                        float* __restrict__ out) {
    int gid = blockIdx.x * blockDim.x + threadIdx.x;
    size_t i = (size_t)gid * 4;

    float4 w = *(const float4*)(y + i);
    ushort4 p;
    p.x = f2bf(w.x); p.y = f2bf(w.y); p.z = f2bf(w.z); p.w = f2bf(w.w);
    *(ushort4*)(y16 + i) = p;
    float sy = w.x * w.x + w.y * w.y + w.z * w.z + w.w * w.w;

#pragma unroll
    for (int mask = 1; mask <= 16; mask <<= 1)
        sy += __shfl_xor(sy, mask, 64);
    if ((threadIdx.x & 31) == 0)
        yn[gid >> 5] = sy;

    if (gid < BS * NN) rowmin[gid] = FINF_BITS;
    if (gid < BS * MM) colmin[gid] = FINF_BITS;
    if (gid == 0) out[0] = 0.0f;
}

// stage one half-K slice (128 rows x 64 k = 16 KB) of y tile via
// global_load_lds width-16, dest lane-order, source chunk-swizzled c^(r&7).
__device__ __forceinline__ void stage_y(const ushort* __restrict__ Yb,
                                        ushort* __restrict__ buf,
                                        int tile, int half, int tid, int wave) {
#pragma unroll
    for (int s = 0; s < 4; ++s) {
        int f = s * 256 + tid;           // 1024 chunks = 128 rows x 8
        int r = f >> 3, cslot = f & 7;
        const ushort* g = Yb + (size_t)(tile * YT + r) * CC + half * 64 +
                          ((cslot ^ (r & 7)) * 8);
        ushort* l = buf + (size_t)(s * 256 + wave * 64) * 8;  // uniform; HW adds lane*16
        __builtin_amdgcn_global_load_lds(
            (const __attribute__((address_space(1))) void*)g,
            (__attribute__((address_space(3))) void*)l, 16, 0, 0);
    }
}

// ---------------------------------------------------------------------------
// main kernel (R15): square 64x64 wave tiles (i=j=4, acc 64 AGPR) to cut LDS
// traffic to 0.5 KB/MFMA (=105 B/cyc at full MFMA rate < 128 B/cyc LDS peak;
// R14's i=4,j=2 needed 155 B/cyc -> LDS-bound). y staged in HALF-K slices
// (128 rows x 64 k = 16 KB) double-buffered via global_load_lds; prefetch
// distance = one compute phase (~620 cyc >> L2 latency). Both xs and ys
// swizzled c^(r&7) -> uniform bank load (R14's 4.2e6 conflicts fixed).
// x staged fp32->bf16 in-kernel + in-LDS norms (R12); XCD-pinned grid (R13);
// no device-scope fences (R11); no launch_bounds coercion (R5/R6).
// ---------------------------------------------------------------------------
__global__ __launch_bounds__(256) void ch_tile(
    const float* __restrict__ Xf, const ushort* __restrict__ Y,
    const float* __restrict__ yn,
    unsigned* __restrict__ rowmin, unsigned* __restrict__ colmin) {

    __shared__ ushort xs[XT * CC];       // 32 KB, chunk-swizzled (r&7)
    __shared__ ushort ys[2][YT * 64];    // 2 x 16 KB half-K slices, swizzled
    __shared__ unsigned coltile[MH];     // 8 KB
    __shared__ unsigned rowtile[XT];     // 0.5 KB
    __shared__ float xnorm[XT];          // 0.5 KB

    const int b  = blockIdx.x;           // 0..7 -> XCD pin (linear id % 8 == b)
    const int xt = blockIdx.y;           // 0..31
    const int mh = blockIdx.z;           // 0..1
    const int n0 = xt * XT;
    const int m0 = mh * MH;
    const int tid  = threadIdx.x;
    const int wave = tid >> 6;           // 0..3
    const int lane = tid & 63;
    const int lc   = lane & 15;          // A/B row, C col
    const int quad = lane >> 4;          // k-chunk, C row group
    const int wm = wave >> 1;            // x half (0/1)
    const int wn = wave & 1;             // y half (0/1)

    const ushort* Yb = Y + ((size_t)b * MM + m0) * CC;

    // ---- stage x tile: fp32 -> bf16 -> swizzled LDS; norms too ----
    const float* Xb = Xf + ((size_t)b * NN + n0) * CC;
    {
        float psum[8];
#pragma unroll
        for (int s = 0; s < 8; ++s) {
            int flat = s * 256 + tid;    // 2048 chunks = 128 rows x 16
            int r = flat >> 4, c = flat & 15;
            float4 v0 = *(const float4*)(Xb + (size_t)r * CC + c * 8);
            float4 v1 = *(const float4*)(Xb + (size_t)r * CC + c * 8 + 4);
            ushort h[8] = {f2bf(v0.x), f2bf(v0.y), f2bf(v0.z), f2bf(v0.w),
                           f2bf(v1.x), f2bf(v1.y), f2bf(v1.z), f2bf(v1.w)};
            *(bf16x8*)(xs + r * CC + (c ^ (r & 7)) * 8) = *(bf16x8*)h;
            psum[s] = v0.x * v0.x + v0.y * v0.y + v0.z * v0.z + v0.w * v0.w +
                      v1.x * v1.x + v1.y * v1.y + v1.z * v1.z + v1.w * v1.w;
        }
#pragma unroll
        for (int mask = 1; mask <= 8; mask <<= 1)
#pragma unroll
            for (int s = 0; s < 8; ++s)
                psum[s] += __shfl_xor(psum[s], mask, 64);
        if ((tid & 15) == 0) {
#pragma unroll
            for (int s = 0; s < 8; ++s)
                xnorm[s * 16 + (tid >> 4)] = psum[s];
        }
    }
    for (int c2 = tid; c2 < MH; c2 += 256) coltile[c2] = FINF_BITS;
    if (tid < XT) rowtile[tid] = FINF_BITS;

    // ---- kick off the pipeline: tile 0, half 0 ----
    stage_y(Yb, ys[0], 0, 0, tid, wave);

    __syncthreads();   // drains x LDS writes + first y slice

    // persistent x norms for this wave's rows
    float xnp[4][4];
#pragma unroll
    for (int i = 0; i < 4; ++i) {
        float4 t = *(const float4*)(&xnorm[wm * 64 + i * 16 + quad * 4]);
        xnp[i][0] = t.x; xnp[i][1] = t.y; xnp[i][2] = t.z; xnp[i][3] = t.w;
    }
    float rm[4][4];
#pragma unroll
    for (int i = 0; i < 4; ++i)
#pragma unroll
        for (int r = 0; r < 4; ++r) rm[i][r] = __builtin_inff();

    const float* ynb = yn + (size_t)b * MM + m0;
    const int xrow = (wm * 64 + lc) * CC;
    const int xsw  = lc & 7;

#pragma unroll 1
    for (int t = 0; t < NMT; ++t) {
        float ynr[4];
        f32x4 acc[4][4];
        const f32x4 z = {0.f, 0.f, 0.f, 0.f};

#pragma unroll
        for (int h = 0; h < 2; ++h) {
            const int p = (2 * t + h) & 1;
            if (t + h) __syncthreads();  // slice p staged; slice p^1 free

            // prefetch next half-K slice into the other buffer
            const int nh = 2 * t + h + 1;
            if (nh < 2 * NMT)
                stage_y(Yb, ys[p ^ 1], nh >> 1, nh & 1, tid, wave);

            if (h == 0) {
#pragma unroll
                for (int j = 0; j < 4; ++j)
                    ynr[j] = ynb[t * YT + wn * 64 + j * 16 + lc];
            }

            const ushort* yl = ys[p];
#pragma unroll
            for (int s2 = 0; s2 < 2; ++s2) {
                const int ktg = h * 2 + s2;
                bf16x8 af[4], yf[4];
                const int cx = ((ktg * 4 + quad) ^ xsw) * 8;
                const int cy = ((s2 * 4 + quad) ^ xsw) * 8;
#pragma unroll
                for (int j = 0; j < 4; ++j)
                    yf[j] = *(const bf16x8*)(yl + (wn * 64 + j * 16 + lc) * 64 + cy);
#pragma unroll
                for (int i = 0; i < 4; ++i)
                    af[i] = *(const bf16x8*)(xs + xrow + i * 16 * CC + cx);
#pragma unroll
                for (int j = 0; j < 4; ++j)
#pragma unroll
                    for (int i = 0; i < 4; ++i)
                        acc[i][j] = __builtin_amdgcn_mfma_f32_16x16x32_bf16(
                            af[i], yf[j], (ktg == 0) ? z : acc[i][j], 0, 0, 0);
            }
        }

        // ---- epilogue: d^2 mins (sqrt/clamp deferred) ----
        float cmv[4];
#pragma unroll
        for (int j = 0; j < 4; ++j) cmv[j] = __builtin_inff();

#pragma unroll
        for (int i = 0; i < 4; ++i) {
#pragma unroll
            for (int j = 0; j < 4; ++j) {
                f32x4 a = acc[i][j];
#pragma unroll
                for (int r = 0; r < 4; ++r) {
                    float d2 = xnp[i][r] + fmaf(-2.0f, a[r], ynr[j]);
                    rm[i][r] = fminf(rm[i][r], d2);
                    cmv[j]   = fminf(cmv[j], d2);
                }
            }
        }

        // col reduce across quads, then LDS atomic
#pragma unroll
        for (int mask = 16; mask <= 32; mask <<= 1)
#pragma unroll
            for (int j = 0; j < 4; ++j)
                cmv[j] = fminf(cmv[j], __shfl_xor(cmv[j], mask, 64));
        if (quad == 0) {
#pragma unroll
            for (int j = 0; j < 4; ++j)
                atomicMin(&coltile[t * YT + wn * 64 + j * 16 + lc],
                          __float_as_uint(fmaxf(cmv[j], 0.0f)));
        }
    }

    // ---- row mins: reduce across the 16 lc lanes, LDS atomic once ----
#pragma unroll
    for (int mask = 1; mask <= 8; mask <<= 1)
#pragma unroll
        for (int i = 0; i < 4; ++i)
#pragma unroll
            for (int r = 0; r < 4; ++r)
                rm[i][r] = fminf(rm[i][r], __shfl_xor(rm[i][r], mask, 64));
    if (lc == 0) {
#pragma unroll
        for (int i = 0; i < 4; ++i)
#pragma unroll
            for (int r = 0; r < 4; ++r)
                atomicMin(&rowtile[wm * 64 + i * 16 + quad * 4 + r],
                          __float_as_uint(fmaxf(rm[i][r], 0.0f)));
    }

    // ---- flush tile minima with global atomics ----
    __syncthreads();
    if (tid < XT)
        atomicMin(&rowmin[(size_t)b * NN + n0 + tid], rowtile[tid]);
    for (int c2 = tid; c2 < MH; c2 += 256)
        atomicMin(&colmin[(size_t)b * MM + m0 + c2], coltile[c2]);
}

// ---------------------------------------------------------------------------
// finalize: total = (sum w1*sqrt(rowmin) + sum w2*sqrt(colmin)) / 2
// ---------------------------------------------------------------------------
__global__ void ch_finalize(const unsigned* __restrict__ rowmin,
                            const unsigned* __restrict__ colmin,
                            const float* __restrict__ w1,
                            const float* __restrict__ w2,
                            float* __restrict__ out) {
    int i = blockIdx.x * blockDim.x + threadIdx.x;
    int stride = gridDim.x * blockDim.x;
    float s = 0.f;
    for (int idx = i; idx < BS * NN; idx += stride)
        s += w1[idx] * sqrtf(__uint_as_float(rowmin[idx])) +
             w2[idx] * sqrtf(__uint_as_float(colmin[idx]));
#pragma unroll
    for (int off = 32; off > 0; off >>= 1) s += __shfl_down(s, off, 64);
    __shared__ float ls[4];
    int lane = threadIdx.x & 63, wv = threadIdx.x >> 6;
    if (lane == 0) ls[wv] = s;
    __syncthreads();
    if (threadIdx.x == 0) {
        float t = ls[0] + ls[1] + ls[2] + ls[3];
        atomicAdd(out, 0.5f * t);
    }
}

extern "C" void kernel_launch(void* const* d_in, const int* in_sizes, int n_in,
                              void* d_out, int out_size, void* d_ws, size_t ws_size,
                              hipStream_t stream) {
    const float* set1 = (const float*)d_in[0];
    const float* set2 = (const float*)d_in[1];
    const float* w1   = (const float*)d_in[2];
    const float* w2   = (const float*)d_in[3];
    float* out = (float*)d_out;

    // workspace layout (~8.5 MiB)
    ushort*   y16    = (ushort*)d_ws;                        // BS*MM*CC bf16 (8 MB)
    float*    yn     = (float*)(y16 + (size_t)BS * MM * CC); // 128 KB
    unsigned* rowmin = (unsigned*)(yn + BS * MM);            // 128 KB (d^2 bits)
    unsigned* colmin = rowmin + BS * NN;                     // 128 KB (d^2 bits)

    ch_prep<<<BS * MM * CC / 4 / 256, 256, 0, stream>>>(
        set2, y16, yn, rowmin, colmin, out);

    dim3 grid(BS, NXT, MM / MH);   // b fastest -> linear id % 8 == b == XCD
    ch_tile<<<grid, 256, 0, stream>>>(set1, y16, yn, rowmin, colmin);

    ch_finalize<<<64, 256, 0, stream>>>(rowmin, colmin, w1, w2, out);
}